// Round 5
// baseline (608.782 us; speedup 1.0000x reference)
//
#include <hip/hip_runtime.h>
#include <hip/hip_bf16.h>
#include <stdint.h>

// TemporalAttention: x[B,T,C] -> qkv proj -> causal MHA -> out proj.
// B=4 T=2048 C=1024 H=16 D=64. Inputs fp32 (established R4: bf16 reading
// NaN'd, fp32 reading finite). Output fp32 this round: R4's 4.73 error ==
// quantitative signature of bf16 written into an fp32 buffer (decorrelated
// same-scale first half + zeroed tail ~= sqrt2*max|ref|). "(bf16, ref=np)"
// in the harness label = bf16-tolerance comparison mode (2% threshold),
// not buffer dtype. Internal compute stays bf16 MFMA (within threshold).
//
// Mechanics frozen from R4 (register staging, no gl2lds, padded LDS,
// barrier-ordered P exchange). Optimize after first pass.

using bf16 = __hip_bfloat16;
typedef __attribute__((ext_vector_type(8))) __bf16 bf16x8;
typedef __attribute__((ext_vector_type(8))) unsigned short u16x8;
typedef __attribute__((ext_vector_type(4))) float f32x4;
typedef unsigned short ushort_t;

#define MFMA16(a, b, c) __builtin_amdgcn_mfma_f32_16x16x32_bf16((a), (b), (c), 0, 0, 0)

__device__ __forceinline__ bf16x8 ld_frag(const ushort_t* p) {
  const u16x8 u = *(const u16x8*)p;
  return __builtin_bit_cast(bf16x8, u);
}

__device__ __forceinline__ ushort_t f2bf(float f) {
  return __builtin_bit_cast(ushort_t, __float2bfloat16(f));
}

// ---------------------------------------------------------------------------
// Dtype detector (kept as a hedge): votes on x's first 4096 u16 halves.
// bf16 Gaussian: ~99.9% of u16s have exponent field in [117,133].
// fp32 Gaussian: hi-halves in range, lo-halves uniform -> ~53%. flag=1: fp32.
// ---------------------------------------------------------------------------
__global__ void detect_dtype(const ushort_t* __restrict__ x, int* __restrict__ flag) {
  __shared__ int red[256];
  const int tid = threadIdx.x;
  int cnt = 0;
  for (int i = tid; i < 4096; i += 256) {
    const int e = (x[i] & 0x7FFF) >> 7;
    cnt += (e >= 117 && e <= 133) ? 1 : 0;
  }
  red[tid] = cnt;
  __syncthreads();
  for (int s = 128; s > 0; s >>= 1) {
    if (tid < s) red[tid] += red[tid + s];
    __syncthreads();
  }
  if (tid == 0) *flag = (red[0] < 3072) ? 1 : 0;
}

// ---------------------------------------------------------------------------
// NT GEMM: C[M,N] = A[M,K] * B[N,K]^T. 128x128 tile, 4 waves 2x2, BK=32,
// 16x16x32 bf16 MFMA, register staging. fp32 operands (flag&&ext) convert
// to bf16 at staging. EPI==0: fp32 store to C0. EPI==1: bf16 scatter
// qkv -> q/k/v in [B,H,T,D].
// ---------------------------------------------------------------------------
template <int EPI>
__global__ __launch_bounds__(256, 2)
void gemm_nt(const void* __restrict__ A, const void* __restrict__ Bw,
             const int* __restrict__ flag, int aExt, int bExt,
             float* __restrict__ C0, bf16* __restrict__ Qo,
             bf16* __restrict__ Ko, bf16* __restrict__ Vo,
             int M, int N, int Kd) {
  __shared__ ushort_t sA[128 * 32];
  __shared__ ushort_t sB[128 * 32];
  const int tid = threadIdx.x;
  const int wave = tid >> 6, lane = tid & 63;
  const int quad = lane >> 4, l16 = lane & 15;
  const int wm = wave >> 1, wn = wave & 1;
  const long m0 = (long)blockIdx.y * 128;
  const long n0 = (long)blockIdx.x * 128;
  const int f = *flag;
  const int aF = aExt ? f : 0;
  const int bF = bExt ? f : 0;

  f32x4 acc[4][4];
#pragma unroll
  for (int i = 0; i < 4; ++i)
#pragma unroll
    for (int j = 0; j < 4; ++j) acc[i][j] = (f32x4){0.f, 0.f, 0.f, 0.f};

  for (int k0 = 0; k0 < Kd; k0 += 32) {
#pragma unroll
    for (int t2 = 0; t2 < 2; ++t2) {
      const int idx = t2 * 256 + tid;  // [0,512)
      const int r = idx >> 2, c = idx & 3;
      const long offA = (m0 + r) * (long)Kd + k0 + c * 8;
      const long offB = (n0 + r) * (long)Kd + k0 + c * 8;
      if (aF) {
        const float* p = (const float*)A + offA;
        const float4 f0 = *(const float4*)p;
        const float4 f1 = *(const float4*)(p + 4);
        u16x8 u;
        u[0] = f2bf(f0.x); u[1] = f2bf(f0.y); u[2] = f2bf(f0.z); u[3] = f2bf(f0.w);
        u[4] = f2bf(f1.x); u[5] = f2bf(f1.y); u[6] = f2bf(f1.z); u[7] = f2bf(f1.w);
        *(u16x8*)&sA[r * 32 + c * 8] = u;
      } else {
        *(u16x8*)&sA[r * 32 + c * 8] = *(const u16x8*)((const ushort_t*)A + offA);
      }
      if (bF) {
        const float* p = (const float*)Bw + offB;
        const float4 f0 = *(const float4*)p;
        const float4 f1 = *(const float4*)(p + 4);
        u16x8 u;
        u[0] = f2bf(f0.x); u[1] = f2bf(f0.y); u[2] = f2bf(f0.z); u[3] = f2bf(f0.w);
        u[4] = f2bf(f1.x); u[5] = f2bf(f1.y); u[6] = f2bf(f1.z); u[7] = f2bf(f1.w);
        *(u16x8*)&sB[r * 32 + c * 8] = u;
      } else {
        *(u16x8*)&sB[r * 32 + c * 8] = *(const u16x8*)((const ushort_t*)Bw + offB);
      }
    }
    __syncthreads();
    bf16x8 af[4], bfr[4];
#pragma unroll
    for (int i = 0; i < 4; ++i) {
      const int r = wm * 64 + i * 16 + l16;
      af[i] = ld_frag(&sA[r * 32 + quad * 8]);
    }
#pragma unroll
    for (int i = 0; i < 4; ++i) {
      const int r = wn * 64 + i * 16 + l16;
      bfr[i] = ld_frag(&sB[r * 32 + quad * 8]);
    }
#pragma unroll
    for (int i = 0; i < 4; ++i)
#pragma unroll
      for (int j = 0; j < 4; ++j) acc[i][j] = MFMA16(af[i], bfr[j], acc[i][j]);
    __syncthreads();
  }

  // epilogue: C/D layout col=lane&15, row=quad*4+reg (m89-verified)
#pragma unroll
  for (int i = 0; i < 4; ++i) {
#pragma unroll
    for (int j = 0; j < 4; ++j) {
#pragma unroll
      for (int reg = 0; reg < 4; ++reg) {
        const long m = m0 + wm * 64 + i * 16 + quad * 4 + reg;
        const long n = n0 + wn * 64 + j * 16 + l16;
        if (EPI == 0) {
          C0[m * N + n] = acc[i][j][reg];  // fp32 output, no rounding
        } else {
          const bf16 v = __float2bfloat16(acc[i][j][reg]);
          const int which = (int)(n >> 10);
          const int h = (int)((n >> 6) & 15);
          const int d = (int)(n & 63);
          const long b = m >> 11;
          const long t = m & 2047;
          bf16* dst = (which == 0) ? Qo : (which == 1) ? Ko : Vo;
          dst[((b * 16 + h) * 2048 + t) * 64 + d] = v;
        }
      }
    }
  }
}

// ---------------------------------------------------------------------------
// Flash attention (causal) — conservative variant (frozen from R3/R4).
// One block per (b*H+h, 64-row Q tile); 4 waves, wave w owns Q rows
// [w*16, w*16+16). bf16 workspace in/out.
// ---------------------------------------------------------------------------
#define ROWQ 72  // padded row stride (ushorts): 64 + 16B pad

__global__ __launch_bounds__(256, 2)
void attn_causal(const bf16* __restrict__ Qg, const bf16* __restrict__ Kg,
                 const bf16* __restrict__ Vg, bf16* __restrict__ Yg) {
  __shared__ ushort_t sQ[64 * ROWQ];
  __shared__ ushort_t sK[64 * ROWQ];
  __shared__ ushort_t sVt[64 * ROWQ];
  __shared__ ushort_t sP[4][16 * ROWQ];
  const int tid = threadIdx.x;
  const int wave = tid >> 6, lane = tid & 63;
  const int quad = lane >> 4, l16 = lane & 15;
  const int qt = blockIdx.x, bh = blockIdx.y;
  const ushort_t* Qb = (const ushort_t*)Qg + ((size_t)bh * 2048 + (size_t)qt * 64) * 64;
  const ushort_t* Kb = (const ushort_t*)Kg + (size_t)bh * 2048 * 64;
  const ushort_t* Vb = (const ushort_t*)Vg + (size_t)bh * 2048 * 64;

#pragma unroll
  for (int t2 = 0; t2 < 2; ++t2) {
    const int idx = t2 * 256 + tid;
    const int r = idx >> 3, c = idx & 7;
    *(u16x8*)&sQ[r * ROWQ + c * 8] = *(const u16x8*)(Qb + r * 64 + c * 8);
  }

  float m_i[4], l_i[4];
  f32x4 oacc[4];
#pragma unroll
  for (int r = 0; r < 4; ++r) {
    m_i[r] = -1e30f;
    l_i[r] = 0.f;
    oacc[r] = (f32x4){0.f, 0.f, 0.f, 0.f};
  }

  __syncthreads();
  bf16x8 qf[2];
  {
    const int r = wave * 16 + l16;  // A-frag: m = lane&15, k = quad*8+j
#pragma unroll
    for (int kk = 0; kk < 2; ++kk)
      qf[kk] = ld_frag(&sQ[r * ROWQ + (kk * 4 + quad) * 8]);
  }
  const int qrow = qt * 64 + wave * 16 + quad * 4;  // + reg

  for (int kvt = 0; kvt <= qt; ++kvt) {
    __syncthreads();
    const ushort_t* Kt = Kb + (size_t)kvt * 64 * 64;
    const ushort_t* Vt = Vb + (size_t)kvt * 64 * 64;
#pragma unroll
    for (int t2 = 0; t2 < 2; ++t2) {
      const int idx = t2 * 256 + tid;
      const int r = idx >> 3, c = idx & 7;
      *(u16x8*)&sK[r * ROWQ + c * 8] = *(const u16x8*)(Kt + r * 64 + c * 8);
    }
#pragma unroll
    for (int t2 = 0; t2 < 2; ++t2) {
      const int idx = t2 * 256 + tid;
      const int key = idx >> 3, dc = idx & 7;
      const u16x8 pk = *(const u16x8*)(Vt + key * 64 + dc * 8);
#pragma unroll
      for (int jj = 0; jj < 8; ++jj) sVt[(dc * 8 + jj) * ROWQ + key] = pk[jj];
    }
    __syncthreads();

    f32x4 s[4];
#pragma unroll
    for (int nt = 0; nt < 4; ++nt) s[nt] = (f32x4){0.f, 0.f, 0.f, 0.f};
#pragma unroll
    for (int nt = 0; nt < 4; ++nt) {
      const int rn = nt * 16 + l16;
#pragma unroll
      for (int kk = 0; kk < 2; ++kk) {
        const bf16x8 kf = ld_frag(&sK[rn * ROWQ + (kk * 4 + quad) * 8]);
        s[nt] = MFMA16(qf[kk], kf, s[nt]);
      }
    }
    const bool diag = (kvt == qt);
#pragma unroll
    for (int nt = 0; nt < 4; ++nt) {
      const int keyg = kvt * 64 + nt * 16 + l16;
#pragma unroll
      for (int reg = 0; reg < 4; ++reg) {
        float v = s[nt][reg] * 0.125f;  // 1/sqrt(64)
        if (diag && keyg > qrow + reg) v = -1e30f;
        s[nt][reg] = v;
      }
    }
#pragma unroll
    for (int reg = 0; reg < 4; ++reg) {
      float rm = fmaxf(fmaxf(s[0][reg], s[1][reg]), fmaxf(s[2][reg], s[3][reg]));
#pragma unroll
      for (int off = 1; off < 16; off <<= 1) rm = fmaxf(rm, __shfl_xor(rm, off, 64));
      const float mnew = fmaxf(m_i[reg], rm);
      float rs = 0.f;
#pragma unroll
      for (int nt = 0; nt < 4; ++nt) {
        const float p = __expf(s[nt][reg] - mnew);
        s[nt][reg] = p;
        rs += p;
      }
#pragma unroll
      for (int off = 1; off < 16; off <<= 1) rs += __shfl_xor(rs, off, 64);
      const float alpha = __expf(m_i[reg] - mnew);
      l_i[reg] = l_i[reg] * alpha + rs;
      m_i[reg] = mnew;
#pragma unroll
      for (int dt = 0; dt < 4; ++dt) oacc[dt][reg] *= alpha;
    }
    ushort_t* sPw = sP[wave];
#pragma unroll
    for (int nt = 0; nt < 4; ++nt) {
#pragma unroll
      for (int reg = 0; reg < 4; ++reg) {
        const int q = quad * 4 + reg;
        const int key = nt * 16 + l16;
        sPw[q * ROWQ + key] = f2bf(s[nt][reg]);
      }
    }
    __syncthreads();
    bf16x8 pf[2];
#pragma unroll
    for (int kk = 0; kk < 2; ++kk)
      pf[kk] = ld_frag(&sPw[l16 * ROWQ + (kk * 4 + quad) * 8]);
#pragma unroll
    for (int dt = 0; dt < 4; ++dt) {
      const int rd = dt * 16 + l16;
#pragma unroll
      for (int kk = 0; kk < 2; ++kk) {
        const bf16x8 vf = ld_frag(&sVt[rd * ROWQ + (kk * 4 + quad) * 8]);
        oacc[dt] = MFMA16(pf[kk], vf, oacc[dt]);
      }
    }
  }

  const int b = bh >> 4, h = bh & 15;
#pragma unroll
  for (int dt = 0; dt < 4; ++dt) {
#pragma unroll
    for (int reg = 0; reg < 4; ++reg) {
      const int t = qt * 64 + wave * 16 + quad * 4 + reg;
      const int d = dt * 16 + l16;
      const float v = oacc[dt][reg] / l_i[reg];
      Yg[(((size_t)b * 2048 + t) * 16 + h) * 64 + d] = __float2bfloat16(v);
    }
  }
}

extern "C" void kernel_launch(void* const* d_in, const int* in_sizes, int n_in,
                              void* d_out, int out_size, void* d_ws, size_t ws_size,
                              hipStream_t stream) {
  const void* x = d_in[0];      // [4,2048,1024] fp32 (runtime-detected)
  const void* w_qkv = d_in[1];  // [3072,1024]
  const void* w_out = d_in[2];  // [1024,1024]
  float* out = (float*)d_out;   // [4,2048,1024] fp32

  const size_t per = (size_t)4 * 16 * 2048 * 64;  // 8.39M elems (16.78 MB bf16)
  bf16* qws = (bf16*)d_ws;  // [B,H,T,D]
  bf16* kws = qws + per;
  bf16* vws = kws + per;
  bf16* yws = vws + per;    // [B,T,H,D] == row-major [token, C]
  int* flag = (int*)(yws + per);
  (void)in_sizes; (void)n_in; (void)out_size; (void)ws_size;

  dim3 blk(256);
  detect_dtype<<<1, 256, 0, stream>>>((const ushort_t*)x, flag);
  gemm_nt<1><<<dim3(24, 64), blk, 0, stream>>>(x, w_qkv, flag, 1, 1, nullptr,
                                               qws, kws, vws, 8192, 3072, 1024);
  attn_causal<<<dim3(32, 64), blk, 0, stream>>>(qws, kws, vws, yws);
  gemm_nt<0><<<dim3(8, 64), blk, 0, stream>>>(yws, w_out, flag, 0, 1, out,
                                              nullptr, nullptr, nullptr,
                                              8192, 1024, 1024);
}

// Round 6
// 349.811 us; speedup vs baseline: 1.7403x; 1.7403x over previous
//
#include <hip/hip_runtime.h>
#include <hip/hip_bf16.h>
#include <stdint.h>

// TemporalAttention: x[B,T,C] -> qkv proj -> causal MHA -> out proj.
// B=4 T=2048 C=1024 H=16 D=64. Inputs fp32, output fp32 (R4/R5-established);
// internal bf16 MFMA.
//
// R5 post-mortem: attn 335us, MfmaUtil 4%, 4e7 LDS conflicts (32 scalar
// ds_write_b16/thread/tile), 18% occupancy (32x qt imbalance). This round:
// S^T/O^T operand-swapped attention (softmax row in 4 lanes, P exchange as
// 4x b64 writes), V pre-transposed by gemm1 epilogue, (qx,31-qx) work
// pairing with shared K/V staging, x pre-converted to bf16.

using bf16 = __hip_bfloat16;
typedef __attribute__((ext_vector_type(8))) __bf16 bf16x8;
typedef __attribute__((ext_vector_type(8))) unsigned short u16x8;
typedef __attribute__((ext_vector_type(4))) unsigned short u16x4;
typedef __attribute__((ext_vector_type(4))) float f32x4;
typedef unsigned short ushort_t;

#define MFMA16(a, b, c) __builtin_amdgcn_mfma_f32_16x16x32_bf16((a), (b), (c), 0, 0, 0)

__device__ __forceinline__ bf16x8 ld_frag(const ushort_t* p) {
  const u16x8 u = *(const u16x8*)p;
  return __builtin_bit_cast(bf16x8, u);
}

__device__ __forceinline__ ushort_t f2bf(float f) {
  return __builtin_bit_cast(ushort_t, __float2bfloat16(f));
}

// ---------------------------------------------------------------------------
// Dtype detector (hedge, established fp32 in practice). flag=1 -> fp32.
// ---------------------------------------------------------------------------
__global__ void detect_dtype(const ushort_t* __restrict__ x, int* __restrict__ flag) {
  __shared__ int red[256];
  const int tid = threadIdx.x;
  int cnt = 0;
  for (int i = tid; i < 4096; i += 256) {
    const int e = (x[i] & 0x7FFF) >> 7;
    cnt += (e >= 117 && e <= 133) ? 1 : 0;
  }
  red[tid] = cnt;
  __syncthreads();
  for (int s = 128; s > 0; s >>= 1) {
    if (tid < s) red[tid] += red[tid + s];
    __syncthreads();
  }
  if (tid == 0) *flag = (red[0] < 3072) ? 1 : 0;
}

// ---------------------------------------------------------------------------
// fp32 -> bf16 conversion (or straight copy if flag==0). n multiple of 8.
// ---------------------------------------------------------------------------
__global__ void cvt_to_bf16(const void* __restrict__ in, ushort_t* __restrict__ out,
                            int n, const int* __restrict__ flag) {
  const int i = (blockIdx.x * 256 + threadIdx.x) * 8;
  if (i >= n) return;
  if (*flag) {
    const float* p = (const float*)in + i;
    const float4 f0 = *(const float4*)p;
    const float4 f1 = *(const float4*)(p + 4);
    u16x8 u;
    u[0] = f2bf(f0.x); u[1] = f2bf(f0.y); u[2] = f2bf(f0.z); u[3] = f2bf(f0.w);
    u[4] = f2bf(f1.x); u[5] = f2bf(f1.y); u[6] = f2bf(f1.z); u[7] = f2bf(f1.w);
    *(u16x8*)(out + i) = u;
  } else {
    *(u16x8*)(out + i) = *(const u16x8*)((const ushort_t*)in + i);
  }
}

// ---------------------------------------------------------------------------
// NT GEMM: C[M,N] = A[M,K] * B[N,K]^T. 128x128 tile, 4 waves 2x2, BK=32,
// 16x16x32 bf16 MFMA, register staging. A always bf16; B fp32-converted
// when bExt&&flag. EPI==0: fp32 store. EPI==1: scatter q/k in [B,H,T,D],
// V TRANSPOSED into [B,H,D,T] (packed b64 along t).
// ---------------------------------------------------------------------------
template <int EPI>
__global__ __launch_bounds__(256, 2)
void gemm_nt(const ushort_t* __restrict__ A, const void* __restrict__ Bw,
             const int* __restrict__ flag, int bExt,
             float* __restrict__ C0, ushort_t* __restrict__ Qo,
             ushort_t* __restrict__ Ko, ushort_t* __restrict__ Vt,
             int M, int N, int Kd) {
  __shared__ ushort_t sA[128 * 32];
  __shared__ ushort_t sB[128 * 32];
  const int tid = threadIdx.x;
  const int wave = tid >> 6, lane = tid & 63;
  const int quad = lane >> 4, l16 = lane & 15;
  const int wm = wave >> 1, wn = wave & 1;
  const long m0 = (long)blockIdx.y * 128;
  const long n0 = (long)blockIdx.x * 128;
  const int bF = bExt ? *flag : 0;

  f32x4 acc[4][4];
#pragma unroll
  for (int i = 0; i < 4; ++i)
#pragma unroll
    for (int j = 0; j < 4; ++j) acc[i][j] = (f32x4){0.f, 0.f, 0.f, 0.f};

  for (int k0 = 0; k0 < Kd; k0 += 32) {
#pragma unroll
    for (int t2 = 0; t2 < 2; ++t2) {
      const int idx = t2 * 256 + tid;  // [0,512)
      const int r = idx >> 2, c = idx & 3;
      const long offA = (m0 + r) * (long)Kd + k0 + c * 8;
      const long offB = (n0 + r) * (long)Kd + k0 + c * 8;
      *(u16x8*)&sA[r * 32 + c * 8] = *(const u16x8*)(A + offA);
      if (bF) {
        const float* p = (const float*)Bw + offB;
        const float4 f0 = *(const float4*)p;
        const float4 f1 = *(const float4*)(p + 4);
        u16x8 u;
        u[0] = f2bf(f0.x); u[1] = f2bf(f0.y); u[2] = f2bf(f0.z); u[3] = f2bf(f0.w);
        u[4] = f2bf(f1.x); u[5] = f2bf(f1.y); u[6] = f2bf(f1.z); u[7] = f2bf(f1.w);
        *(u16x8*)&sB[r * 32 + c * 8] = u;
      } else {
        *(u16x8*)&sB[r * 32 + c * 8] = *(const u16x8*)((const ushort_t*)Bw + offB);
      }
    }
    __syncthreads();
    bf16x8 af[4], bfr[4];
#pragma unroll
    for (int i = 0; i < 4; ++i) {
      const int r = wm * 64 + i * 16 + l16;
      af[i] = ld_frag(&sA[r * 32 + quad * 8]);
    }
#pragma unroll
    for (int i = 0; i < 4; ++i) {
      const int r = wn * 64 + i * 16 + l16;
      bfr[i] = ld_frag(&sB[r * 32 + quad * 8]);
    }
#pragma unroll
    for (int i = 0; i < 4; ++i)
#pragma unroll
      for (int j = 0; j < 4; ++j) acc[i][j] = MFMA16(af[i], bfr[j], acc[i][j]);
    __syncthreads();
  }

  // epilogue: C/D layout col=lane&15, row=quad*4+reg (m89-verified)
#pragma unroll
  for (int i = 0; i < 4; ++i) {
#pragma unroll
    for (int j = 0; j < 4; ++j) {
      if (EPI == 0) {
#pragma unroll
        for (int reg = 0; reg < 4; ++reg) {
          const long m = m0 + wm * 64 + i * 16 + quad * 4 + reg;
          const long n = n0 + wn * 64 + j * 16 + l16;
          C0[m * N + n] = acc[i][j][reg];
        }
      } else {
        const long n = n0 + wn * 64 + j * 16 + l16;
        const int which = (int)(n >> 10);  // block-uniform (128 | 1024)
        const int h = (int)((n >> 6) & 15);
        const int d = (int)(n & 63);
        const long mbase = m0 + wm * 64 + i * 16 + quad * 4;
        const long b = mbase >> 11;  // 128-tile never straddles b
        const long tb = mbase & 2047;
        if (which == 2) {
          // V^T [B,H,D,T]: 4 regs = 4 consecutive t -> one b64 store
          u16x4 pk;
#pragma unroll
          for (int reg = 0; reg < 4; ++reg) pk[reg] = f2bf(acc[i][j][reg]);
          *(u16x4*)&Vt[((b * 16 + h) * 64 + d) * 2048 + tb] = pk;
        } else {
          ushort_t* dst = (which == 0) ? Qo : Ko;
#pragma unroll
          for (int reg = 0; reg < 4; ++reg)
            dst[((b * 16 + h) * 2048 + tb + reg) * 64 + d] = f2bf(acc[i][j][reg]);
        }
      }
    }
  }
}

// ---------------------------------------------------------------------------
// Flash attention (causal), S^T/O^T formulation.
// Block = (qx, bh): processes q-tiles qtA=qx and qtB=31-qx (uniform 33 KV
// tiles of work). Wave w owns q rows [w*16,w*16+16) of each tile.
// S^T = K·Q^T via MFMA(kf,qf): C row=key(quad*4+reg), col=q(l16) -> softmax
// row q lives in 4 lanes; m/l are per-lane scalars; 2 shuffles per reduce.
// P store: per nt one b64 (4 consecutive keys) into sP[q][key]; PV B-frag
// = b128 read of sP row. O^T via MFMA(vf,pf): row=d, col=q. V arrives
// pre-transposed [B,H,D,T] from gemm1.
// ---------------------------------------------------------------------------
#define RS 72  // LDS row stride in ushorts (64 + 16B pad)

__device__ __forceinline__ void attn_tile(const bf16x8 qf[2], const ushort_t* sK,
                                          const ushort_t* sV, ushort_t* sPw,
                                          int kv, int qg, int quad, int l16,
                                          float& m_i, float& l_i, f32x4* oacc) {
  f32x4 s[4];
#pragma unroll
  for (int nt = 0; nt < 4; ++nt) s[nt] = (f32x4){0.f, 0.f, 0.f, 0.f};
#pragma unroll
  for (int nt = 0; nt < 4; ++nt) {
#pragma unroll
    for (int kk = 0; kk < 2; ++kk) {
      const bf16x8 kf = ld_frag(&sK[(nt * 16 + l16) * RS + (kk * 4 + quad) * 8]);
      s[nt] = MFMA16(kf, qf[kk], s[nt]);  // row=key, col=q
    }
  }
  const int kb = kv * 64 + quad * 4;
  float rmax = -1e30f;
#pragma unroll
  for (int nt = 0; nt < 4; ++nt) {
#pragma unroll
    for (int reg = 0; reg < 4; ++reg) {
      float v = s[nt][reg] * 0.125f;  // 1/sqrt(64)
      if (kb + nt * 16 + reg > qg) v = -1e30f;
      s[nt][reg] = v;
      rmax = fmaxf(rmax, v);
    }
  }
  rmax = fmaxf(rmax, __shfl_xor(rmax, 16, 64));
  rmax = fmaxf(rmax, __shfl_xor(rmax, 32, 64));
  const float mnew = fmaxf(m_i, rmax);
  float rs = 0.f;
#pragma unroll
  for (int nt = 0; nt < 4; ++nt) {
#pragma unroll
    for (int reg = 0; reg < 4; ++reg) {
      const float p = __expf(s[nt][reg] - mnew);
      s[nt][reg] = p;
      rs += p;
    }
  }
  rs += __shfl_xor(rs, 16, 64);
  rs += __shfl_xor(rs, 32, 64);
  const float alpha = __expf(m_i - mnew);
  l_i = l_i * alpha + rs;
  m_i = mnew;
#pragma unroll
  for (int dt = 0; dt < 4; ++dt) oacc[dt] *= alpha;

  __threadfence_block();  // WAR: prior sP reads drain before rewrite
#pragma unroll
  for (int nt = 0; nt < 4; ++nt) {
    u16x4 pk;
#pragma unroll
    for (int reg = 0; reg < 4; ++reg) pk[reg] = f2bf(s[nt][reg]);
    *(u16x4*)&sPw[l16 * RS + nt * 16 + quad * 4] = pk;
  }
  __threadfence_block();  // RAW: writes before reads (intra-wave, DS in-order)
  bf16x8 pf[2];
#pragma unroll
  for (int kk = 0; kk < 2; ++kk)
    pf[kk] = ld_frag(&sPw[l16 * RS + kk * 32 + quad * 8]);
#pragma unroll
  for (int dt = 0; dt < 4; ++dt) {
#pragma unroll
    for (int kk = 0; kk < 2; ++kk) {
      const bf16x8 vf = ld_frag(&sV[(dt * 16 + l16) * RS + (kk * 4 + quad) * 8]);
      oacc[dt] = MFMA16(vf, pf[kk], oacc[dt]);  // row=d, col=q
    }
  }
}

__global__ __launch_bounds__(256, 4)
void attn_causal(const ushort_t* __restrict__ Qg, const ushort_t* __restrict__ Kg,
                 const ushort_t* __restrict__ Vt, ushort_t* __restrict__ Yg) {
  __shared__ ushort_t sK[64 * RS];
  __shared__ ushort_t sV[64 * RS];
  __shared__ ushort_t sPQ[64 * RS];  // sQ staging pre-loop; sP[wave] in loop
  const int tid = threadIdx.x;
  const int wave = tid >> 6, lane = tid & 63;
  const int quad = lane >> 4, l16 = lane & 15;
  const int qx = blockIdx.x, bh = blockIdx.y;
  const int qtA = qx, qtB = 31 - qx;
  const size_t base = (size_t)bh * 2048 * 64;
  ushort_t* sPw = sPQ + wave * 16 * RS;

  // stage Q tile A -> qfA, then tile B -> qfB (sPQ reused)
  bf16x8 qfA[2], qfB[2];
#pragma unroll
  for (int tile = 0; tile < 2; ++tile) {
    const int qt = tile ? qtB : qtA;
#pragma unroll
    for (int t2 = 0; t2 < 2; ++t2) {
      const int idx = t2 * 256 + tid;
      const int r = idx >> 3, c = idx & 7;
      *(u16x8*)&sPQ[r * RS + c * 8] =
          *(const u16x8*)(Qg + base + (size_t)(qt * 64 + r) * 64 + c * 8);
    }
    __syncthreads();
#pragma unroll
    for (int kk = 0; kk < 2; ++kk) {
      const bf16x8 f = ld_frag(&sPQ[(wave * 16 + l16) * RS + (kk * 4 + quad) * 8]);
      if (tile) qfB[kk] = f; else qfA[kk] = f;
    }
    __syncthreads();
  }

  float mA = -1e30f, lA = 0.f, mB = -1e30f, lB = 0.f;
  f32x4 oA[4], oB[4];
#pragma unroll
  for (int dt = 0; dt < 4; ++dt) {
    oA[dt] = (f32x4){0.f, 0.f, 0.f, 0.f};
    oB[dt] = (f32x4){0.f, 0.f, 0.f, 0.f};
  }
  const int qgA = qtA * 64 + wave * 16 + l16;
  const int qgB = qtB * 64 + wave * 16 + l16;

  for (int kv = 0; kv <= qtB; ++kv) {
    __syncthreads();  // all waves done with sK/sV of prev iter
#pragma unroll
    for (int t2 = 0; t2 < 2; ++t2) {
      const int idx = t2 * 256 + tid;
      const int r = idx >> 3, c = idx & 7;
      *(u16x8*)&sK[r * RS + c * 8] =
          *(const u16x8*)(Kg + base + (size_t)(kv * 64 + r) * 64 + c * 8);
      *(u16x8*)&sV[r * RS + c * 8] =
          *(const u16x8*)(Vt + base + (size_t)r * 2048 + kv * 64 + c * 8);
    }
    __syncthreads();
    attn_tile(qfB, sK, sV, sPw, kv, qgB, quad, l16, mB, lB, oB);
    if (kv <= qtA)
      attn_tile(qfA, sK, sV, sPw, kv, qgA, quad, l16, mA, lA, oA);
  }

  // epilogue: O^T regs -> y [B,T,H,D]; 4 consecutive d per b64 store
  const int b = bh >> 4, h = bh & 15;
#pragma unroll
  for (int tile = 0; tile < 2; ++tile) {
    const int qt = tile ? qtB : qtA;
    const float linv = 1.f / (tile ? lB : lA);
    const f32x4* o = tile ? oB : oA;
    const int t = qt * 64 + wave * 16 + l16;
#pragma unroll
    for (int dt = 0; dt < 4; ++dt) {
      u16x4 pk;
#pragma unroll
      for (int reg = 0; reg < 4; ++reg) pk[reg] = f2bf(o[dt][reg] * linv);
      *(u16x4*)&Yg[(((size_t)b * 2048 + t) * 16 + h) * 64 + dt * 16 + quad * 4] = pk;
    }
  }
}

extern "C" void kernel_launch(void* const* d_in, const int* in_sizes, int n_in,
                              void* d_out, int out_size, void* d_ws, size_t ws_size,
                              hipStream_t stream) {
  const void* x = d_in[0];      // [4,2048,1024] fp32
  const void* w_qkv = d_in[1];  // [3072,1024] fp32
  const void* w_out = d_in[2];  // [1024,1024] fp32
  float* out = (float*)d_out;   // [4,2048,1024] fp32

  const size_t per = (size_t)4 * 16 * 2048 * 64;  // 8.39M elems
  ushort_t* qws = (ushort_t*)d_ws;   // [B,H,T,D]
  ushort_t* kws = qws + per;         // [B,H,T,D]
  ushort_t* vTws = kws + per;        // [B,H,D,T]  (transposed V)
  ushort_t* xyws = vTws + per;       // xbf pre-gemm1, then y [B,T,H,D]
  int* flag = (int*)(xyws + per);
  (void)in_sizes; (void)n_in; (void)out_size; (void)ws_size;

  dim3 blk(256);
  detect_dtype<<<1, 256, 0, stream>>>((const ushort_t*)x, flag);
  cvt_to_bf16<<<4096, 256, 0, stream>>>(x, xyws, (int)per, flag);
  gemm_nt<1><<<dim3(24, 64), blk, 0, stream>>>(xyws, w_qkv, flag, 1, nullptr,
                                               qws, kws, vTws, 8192, 3072, 1024);
  attn_causal<<<dim3(16, 64), blk, 0, stream>>>(qws, kws, vTws, xyws);
  gemm_nt<0><<<dim3(8, 64), blk, 0, stream>>>(xyws, w_out, flag, 1, out,
                                              nullptr, nullptr, nullptr,
                                              8192, 1024, 1024);
}

// Round 7
// 281.382 us; speedup vs baseline: 2.1635x; 1.2432x over previous
//
#include <hip/hip_runtime.h>
#include <hip/hip_bf16.h>
#include <stdint.h>

// TemporalAttention: x[B,T,C] -> qkv proj -> causal MHA -> out proj.
// B=4 T=2048 C=1024 H=16 D=64. Inputs fp32, output fp32; internal bf16 MFMA.
//
// R6 post-mortem: attn fixed (S^T formulation; <122us). gemm1 now top:
// 123us, MfmaUtil 16%, all pipes idle -> staging-latency-bound (register
// staging + in-stage fp32 cvt). This round: m97-verbatim gl2lds width-16
// staging in both GEMMs + one-shot bf16 pre-conversion of weights.

using bf16 = __hip_bfloat16;
typedef __attribute__((ext_vector_type(8))) __bf16 bf16x8;
typedef __attribute__((ext_vector_type(8))) unsigned short u16x8;
typedef __attribute__((ext_vector_type(4))) unsigned short u16x4;
typedef __attribute__((ext_vector_type(4))) float f32x4;
typedef unsigned short ushort_t;

#define MFMA16(a, b, c) __builtin_amdgcn_mfma_f32_16x16x32_bf16((a), (b), (c), 0, 0, 0)

__device__ __forceinline__ bf16x8 ld_frag(const ushort_t* p) {
  const u16x8 u = *(const u16x8*)p;
  return __builtin_bit_cast(bf16x8, u);
}

__device__ __forceinline__ ushort_t f2bf(float f) {
  return __builtin_bit_cast(ushort_t, __float2bfloat16(f));
}

// async global->LDS, 16B/lane; lds base wave-uniform, lane l -> base+l*16.
__device__ __forceinline__ void gl2lds16(const void* g, void* lds) {
  __builtin_amdgcn_global_load_lds((const __attribute__((address_space(1))) void*)g,
                                   (__attribute__((address_space(3))) void*)lds,
                                   16, 0, 0);
}

// ---------------------------------------------------------------------------
// Dtype detector (hedge; fp32 established). flag=1 -> fp32.
// ---------------------------------------------------------------------------
__global__ void detect_dtype(const ushort_t* __restrict__ x, int* __restrict__ flag) {
  __shared__ int red[256];
  const int tid = threadIdx.x;
  int cnt = 0;
  for (int i = tid; i < 4096; i += 256) {
    const int e = (x[i] & 0x7FFF) >> 7;
    cnt += (e >= 117 && e <= 133) ? 1 : 0;
  }
  red[tid] = cnt;
  __syncthreads();
  for (int s = 128; s > 0; s >>= 1) {
    if (tid < s) red[tid] += red[tid + s];
    __syncthreads();
  }
  if (tid == 0) *flag = (red[0] < 3072) ? 1 : 0;
}

// ---------------------------------------------------------------------------
// fp32 -> bf16 (or copy if flag==0). n multiple of 2048.
// ---------------------------------------------------------------------------
__global__ void cvt_to_bf16(const void* __restrict__ in, ushort_t* __restrict__ out,
                            int n, const int* __restrict__ flag) {
  const int i = (blockIdx.x * 256 + threadIdx.x) * 8;
  if (i >= n) return;
  if (*flag) {
    const float* p = (const float*)in + i;
    const float4 f0 = *(const float4*)p;
    const float4 f1 = *(const float4*)(p + 4);
    u16x8 u;
    u[0] = f2bf(f0.x); u[1] = f2bf(f0.y); u[2] = f2bf(f0.z); u[3] = f2bf(f0.w);
    u[4] = f2bf(f1.x); u[5] = f2bf(f1.y); u[6] = f2bf(f1.z); u[7] = f2bf(f1.w);
    *(u16x8*)(out + i) = u;
  } else {
    *(u16x8*)(out + i) = *(const u16x8*)((const ushort_t*)in + i);
  }
}

// ---------------------------------------------------------------------------
// NT GEMM: C[M,N] = A[M,K]*B[N,K]^T. 128x128 tile, 4 waves 2x2, BK=32,
// 16x16x32 bf16 MFMA. A: bf16, gl2lds staging (m97-verbatim, plain layout).
// B: bf16 via gl2lds when bF==0; fp32 register-staged+cvt when bF==1
// (ws-starved fallback). EPI==0: fp32 store. EPI==1: scatter q/k [B,H,T,D],
// V transposed [B,H,D,T].
// ---------------------------------------------------------------------------
template <int EPI>
__global__ __launch_bounds__(256, 2)
void gemm_nt(const ushort_t* __restrict__ A, const void* __restrict__ Bw,
             const int* __restrict__ flag, int bExt,
             float* __restrict__ C0, ushort_t* __restrict__ Qo,
             ushort_t* __restrict__ Ko, ushort_t* __restrict__ Vt,
             int M, int N, int Kd) {
  __shared__ ushort_t sA[128 * 32];
  __shared__ ushort_t sB[128 * 32];
  const int tid = threadIdx.x;
  const int wave = tid >> 6, lane = tid & 63;
  const int quad = lane >> 4, l16 = lane & 15;
  const int wm = wave >> 1, wn = wave & 1;
  const long m0 = (long)blockIdx.y * 128;
  const long n0 = (long)blockIdx.x * 128;
  const int bF = bExt ? *flag : 0;

  f32x4 acc[4][4];
#pragma unroll
  for (int i = 0; i < 4; ++i)
#pragma unroll
    for (int j = 0; j < 4; ++j) acc[i][j] = (f32x4){0.f, 0.f, 0.f, 0.f};

  for (int k0 = 0; k0 < Kd; k0 += 32) {
#pragma unroll
    for (int j = 0; j < 2; ++j) {
      const int chunk = wave * 2 + j;     // wave-uniform LDS base
      const int idx = chunk * 64 + lane;  // 0..511: 16B chunk per lane
      const int r = idx >> 2, c = idx & 3;
      gl2lds16(A + (m0 + r) * (long)Kd + k0 + c * 8, (char*)sA + chunk * 1024);
    }
    if (!bF) {
#pragma unroll
      for (int j = 0; j < 2; ++j) {
        const int chunk = wave * 2 + j;
        const int idx = chunk * 64 + lane;
        const int r = idx >> 2, c = idx & 3;
        gl2lds16((const ushort_t*)Bw + (n0 + r) * (long)Kd + k0 + c * 8,
                 (char*)sB + chunk * 1024);
      }
    } else {
#pragma unroll
      for (int t2 = 0; t2 < 2; ++t2) {
        const int idx = t2 * 256 + tid;
        const int r = idx >> 2, c = idx & 3;
        const float* p = (const float*)Bw + (n0 + r) * (long)Kd + k0 + c * 8;
        const float4 f0 = *(const float4*)p;
        const float4 f1 = *(const float4*)(p + 4);
        u16x8 u;
        u[0] = f2bf(f0.x); u[1] = f2bf(f0.y); u[2] = f2bf(f0.z); u[3] = f2bf(f0.w);
        u[4] = f2bf(f1.x); u[5] = f2bf(f1.y); u[6] = f2bf(f1.z); u[7] = f2bf(f1.w);
        *(u16x8*)&sB[r * 32 + c * 8] = u;
      }
    }
    __syncthreads();
    bf16x8 af[4], bfr[4];
#pragma unroll
    for (int i = 0; i < 4; ++i) {
      const int r = wm * 64 + i * 16 + l16;
      af[i] = ld_frag(&sA[r * 32 + quad * 8]);
    }
#pragma unroll
    for (int i = 0; i < 4; ++i) {
      const int r = wn * 64 + i * 16 + l16;
      bfr[i] = ld_frag(&sB[r * 32 + quad * 8]);
    }
#pragma unroll
    for (int i = 0; i < 4; ++i)
#pragma unroll
      for (int j = 0; j < 4; ++j) acc[i][j] = MFMA16(af[i], bfr[j], acc[i][j]);
    __syncthreads();
  }

  // epilogue: C/D layout col=lane&15, row=quad*4+reg (m89-verified)
#pragma unroll
  for (int i = 0; i < 4; ++i) {
#pragma unroll
    for (int j = 0; j < 4; ++j) {
      if (EPI == 0) {
#pragma unroll
        for (int reg = 0; reg < 4; ++reg) {
          const long m = m0 + wm * 64 + i * 16 + quad * 4 + reg;
          const long n = n0 + wn * 64 + j * 16 + l16;
          C0[m * N + n] = acc[i][j][reg];
        }
      } else {
        const long n = n0 + wn * 64 + j * 16 + l16;
        const int which = (int)(n >> 10);  // block-uniform
        const int h = (int)((n >> 6) & 15);
        const int d = (int)(n & 63);
        const long mbase = m0 + wm * 64 + i * 16 + quad * 4;
        const long b = mbase >> 11;
        const long tb = mbase & 2047;
        if (which == 2) {
          u16x4 pk;
#pragma unroll
          for (int reg = 0; reg < 4; ++reg) pk[reg] = f2bf(acc[i][j][reg]);
          *(u16x4*)&Vt[((b * 16 + h) * 64 + d) * 2048 + tb] = pk;
        } else {
          ushort_t* dst = (which == 0) ? Qo : Ko;
#pragma unroll
          for (int reg = 0; reg < 4; ++reg)
            dst[((b * 16 + h) * 2048 + tb + reg) * 64 + d] = f2bf(acc[i][j][reg]);
        }
      }
    }
  }
}

// ---------------------------------------------------------------------------
// Flash attention (causal), S^T/O^T formulation — unchanged from R6.
// ---------------------------------------------------------------------------
#define RS 72  // LDS row stride in ushorts (64 + 16B pad)

__device__ __forceinline__ void attn_tile(const bf16x8 qf[2], const ushort_t* sK,
                                          const ushort_t* sV, ushort_t* sPw,
                                          int kv, int qg, int quad, int l16,
                                          float& m_i, float& l_i, f32x4* oacc) {
  f32x4 s[4];
#pragma unroll
  for (int nt = 0; nt < 4; ++nt) s[nt] = (f32x4){0.f, 0.f, 0.f, 0.f};
#pragma unroll
  for (int nt = 0; nt < 4; ++nt) {
#pragma unroll
    for (int kk = 0; kk < 2; ++kk) {
      const bf16x8 kf = ld_frag(&sK[(nt * 16 + l16) * RS + (kk * 4 + quad) * 8]);
      s[nt] = MFMA16(kf, qf[kk], s[nt]);  // row=key, col=q
    }
  }
  const int kb = kv * 64 + quad * 4;
  float rmax = -1e30f;
#pragma unroll
  for (int nt = 0; nt < 4; ++nt) {
#pragma unroll
    for (int reg = 0; reg < 4; ++reg) {
      float v = s[nt][reg] * 0.125f;  // 1/sqrt(64)
      if (kb + nt * 16 + reg > qg) v = -1e30f;
      s[nt][reg] = v;
      rmax = fmaxf(rmax, v);
    }
  }
  rmax = fmaxf(rmax, __shfl_xor(rmax, 16, 64));
  rmax = fmaxf(rmax, __shfl_xor(rmax, 32, 64));
  const float mnew = fmaxf(m_i, rmax);
  float rs = 0.f;
#pragma unroll
  for (int nt = 0; nt < 4; ++nt) {
#pragma unroll
    for (int reg = 0; reg < 4; ++reg) {
      const float p = __expf(s[nt][reg] - mnew);
      s[nt][reg] = p;
      rs += p;
    }
  }
  rs += __shfl_xor(rs, 16, 64);
  rs += __shfl_xor(rs, 32, 64);
  const float alpha = __expf(m_i - mnew);
  l_i = l_i * alpha + rs;
  m_i = mnew;
#pragma unroll
  for (int dt = 0; dt < 4; ++dt) oacc[dt] *= alpha;

  __threadfence_block();  // WAR: prior sP reads drain before rewrite
#pragma unroll
  for (int nt = 0; nt < 4; ++nt) {
    u16x4 pk;
#pragma unroll
    for (int reg = 0; reg < 4; ++reg) pk[reg] = f2bf(s[nt][reg]);
    *(u16x4*)&sPw[l16 * RS + nt * 16 + quad * 4] = pk;
  }
  __threadfence_block();  // RAW: writes before reads
  bf16x8 pf[2];
#pragma unroll
  for (int kk = 0; kk < 2; ++kk)
    pf[kk] = ld_frag(&sPw[l16 * RS + kk * 32 + quad * 8]);
#pragma unroll
  for (int dt = 0; dt < 4; ++dt) {
#pragma unroll
    for (int kk = 0; kk < 2; ++kk) {
      const bf16x8 vf = ld_frag(&sV[(dt * 16 + l16) * RS + (kk * 4 + quad) * 8]);
      oacc[dt] = MFMA16(vf, pf[kk], oacc[dt]);  // row=d, col=q
    }
  }
}

__global__ __launch_bounds__(256, 4)
void attn_causal(const ushort_t* __restrict__ Qg, const ushort_t* __restrict__ Kg,
                 const ushort_t* __restrict__ Vt, ushort_t* __restrict__ Yg) {
  __shared__ ushort_t sK[64 * RS];
  __shared__ ushort_t sV[64 * RS];
  __shared__ ushort_t sPQ[64 * RS];
  const int tid = threadIdx.x;
  const int wave = tid >> 6, lane = tid & 63;
  const int quad = lane >> 4, l16 = lane & 15;
  const int qx = blockIdx.x, bh = blockIdx.y;
  const int qtA = qx, qtB = 31 - qx;
  const size_t base = (size_t)bh * 2048 * 64;
  ushort_t* sPw = sPQ + wave * 16 * RS;

  bf16x8 qfA[2], qfB[2];
#pragma unroll
  for (int tile = 0; tile < 2; ++tile) {
    const int qt = tile ? qtB : qtA;
#pragma unroll
    for (int t2 = 0; t2 < 2; ++t2) {
      const int idx = t2 * 256 + tid;
      const int r = idx >> 3, c = idx & 7;
      *(u16x8*)&sPQ[r * RS + c * 8] =
          *(const u16x8*)(Qg + base + (size_t)(qt * 64 + r) * 64 + c * 8);
    }
    __syncthreads();
#pragma unroll
    for (int kk = 0; kk < 2; ++kk) {
      const bf16x8 f = ld_frag(&sPQ[(wave * 16 + l16) * RS + (kk * 4 + quad) * 8]);
      if (tile) qfB[kk] = f; else qfA[kk] = f;
    }
    __syncthreads();
  }

  float mA = -1e30f, lA = 0.f, mB = -1e30f, lB = 0.f;
  f32x4 oA[4], oB[4];
#pragma unroll
  for (int dt = 0; dt < 4; ++dt) {
    oA[dt] = (f32x4){0.f, 0.f, 0.f, 0.f};
    oB[dt] = (f32x4){0.f, 0.f, 0.f, 0.f};
  }
  const int qgA = qtA * 64 + wave * 16 + l16;
  const int qgB = qtB * 64 + wave * 16 + l16;

  for (int kv = 0; kv <= qtB; ++kv) {
    __syncthreads();
#pragma unroll
    for (int t2 = 0; t2 < 2; ++t2) {
      const int idx = t2 * 256 + tid;
      const int r = idx >> 3, c = idx & 7;
      *(u16x8*)&sK[r * RS + c * 8] =
          *(const u16x8*)(Kg + base + (size_t)(kv * 64 + r) * 64 + c * 8);
      *(u16x8*)&sV[r * RS + c * 8] =
          *(const u16x8*)(Vt + base + (size_t)r * 2048 + kv * 64 + c * 8);
    }
    __syncthreads();
    attn_tile(qfB, sK, sV, sPw, kv, qgB, quad, l16, mB, lB, oB);
    if (kv <= qtA)
      attn_tile(qfA, sK, sV, sPw, kv, qgA, quad, l16, mA, lA, oA);
  }

  const int b = bh >> 4, h = bh & 15;
#pragma unroll
  for (int tile = 0; tile < 2; ++tile) {
    const int qt = tile ? qtB : qtA;
    const float linv = 1.f / (tile ? lB : lA);
    const f32x4* o = tile ? oB : oA;
    const int t = qt * 64 + wave * 16 + l16;
#pragma unroll
    for (int dt = 0; dt < 4; ++dt) {
      u16x4 pk;
#pragma unroll
      for (int reg = 0; reg < 4; ++reg) pk[reg] = f2bf(o[dt][reg] * linv);
      *(u16x4*)&Yg[(((size_t)b * 2048 + t) * 16 + h) * 64 + dt * 16 + quad * 4] = pk;
    }
  }
}

extern "C" void kernel_launch(void* const* d_in, const int* in_sizes, int n_in,
                              void* d_out, int out_size, void* d_ws, size_t ws_size,
                              hipStream_t stream) {
  const void* x = d_in[0];      // [4,2048,1024] fp32
  const void* w_qkv = d_in[1];  // [3072,1024] fp32
  const void* w_out = d_in[2];  // [1024,1024] fp32
  float* out = (float*)d_out;   // [4,2048,1024] fp32

  const size_t per = (size_t)4 * 16 * 2048 * 64;  // 8.39M elems
  const size_t nwqkv = (size_t)3072 * 1024;       // 3.15M
  const size_t nwout = (size_t)1024 * 1024;       // 1.05M
  ushort_t* qws = (ushort_t*)d_ws;   // [B,H,T,D]
  ushort_t* kws = qws + per;         // [B,H,T,D]
  ushort_t* vTws = kws + per;        // [B,H,D,T]
  ushort_t* xyws = vTws + per;       // xbf for gemm1, then y [B,T,H,D]
  ushort_t* wqkvb = xyws + per;      // bf16 w_qkv
  ushort_t* woutb = wqkvb + nwqkv;   // bf16 w_out
  int* flag = (int*)(woutb + nwout);
  const size_t need = (size_t)(4 * per + nwqkv + nwout) * 2 + 16;
  const bool pre = ws_size >= need;  // stable across calls (graph-safe)
  (void)in_sizes; (void)n_in; (void)out_size;

  dim3 blk(256);
  if (!pre) flag = (int*)(xyws + per);
  detect_dtype<<<1, 256, 0, stream>>>((const ushort_t*)x, flag);
  cvt_to_bf16<<<4096, 256, 0, stream>>>(x, xyws, (int)per, flag);
  if (pre) {
    cvt_to_bf16<<<1536, 256, 0, stream>>>(w_qkv, wqkvb, (int)nwqkv, flag);
    cvt_to_bf16<<<512, 256, 0, stream>>>(w_out, woutb, (int)nwout, flag);
    gemm_nt<1><<<dim3(24, 64), blk, 0, stream>>>(xyws, wqkvb, flag, 0, nullptr,
                                                 qws, kws, vTws, 8192, 3072, 1024);
    attn_causal<<<dim3(16, 64), blk, 0, stream>>>(qws, kws, vTws, xyws);
    gemm_nt<0><<<dim3(8, 64), blk, 0, stream>>>(xyws, woutb, flag, 0, out,
                                                nullptr, nullptr, nullptr,
                                                8192, 1024, 1024);
  } else {
    gemm_nt<1><<<dim3(24, 64), blk, 0, stream>>>(xyws, w_qkv, flag, 1, nullptr,
                                                 qws, kws, vTws, 8192, 3072, 1024);
    attn_causal<<<dim3(16, 64), blk, 0, stream>>>(qws, kws, vTws, xyws);
    gemm_nt<0><<<dim3(8, 64), blk, 0, stream>>>(xyws, w_out, flag, 1, out,
                                                nullptr, nullptr, nullptr,
                                                8192, 1024, 1024);
  }
}